// Round 3
// baseline (601.893 us; speedup 1.0000x reference)
//
#include <hip/hip_runtime.h>
#include <hip/hip_bf16.h>

#define T_LEN 8192
#define H_DIM 512
#define P_DIM 512
#define CS 32
#define NB (T_LEN / CS)   // 256 chunks

// ---------------------------------------------------------------------------
// Precompute (double precision): lambda_bar (P complex, f64),
// bbarT[h][2p+c] = ((lbar-1)/lam * b~)[p,h]  (f32 for GEMM),
// B2[2p][h] = c[h][p][0], B2[2p+1][h] = -c[h][p][1]   (f32 for GEMM)
// One thread per p.
// ---------------------------------------------------------------------------
__global__ void precompute_kernel(const float* __restrict__ lambda_real,
                                  const float* __restrict__ lambda_imag,
                                  const float* __restrict__ b,
                                  const float* __restrict__ c,
                                  const float* __restrict__ log_step,
                                  double* __restrict__ lbar,
                                  float* __restrict__ bbarT,
                                  float* __restrict__ B2) {
    int p = blockIdx.x * blockDim.x + threadIdx.x;
    if (p >= P_DIM) return;
    double lr = fmin((double)lambda_real[p], -1e-4);
    double li = (double)lambda_imag[p];
    double step = exp((double)log_step[p]);          // STEP_RESCALE = 1
    double er = exp(lr * step);
    double ang = li * step;
    double lbr = er * cos(ang);
    double lbi = er * sin(ang);
    lbar[2 * p] = lbr;
    lbar[2 * p + 1] = lbi;
    // coef = (lbar - 1) / lam  (complex divide, f64)
    double nr = lbr - 1.0, ni = lbi;
    double den = lr * lr + li * li;
    double cr = (nr * lr + ni * li) / den;
    double ci = (ni * lr - nr * li) / den;
    for (int h = 0; h < H_DIM; ++h) {
        double br = (double)b[((size_t)p * H_DIM + h) * 2];
        double bi = (double)b[((size_t)p * H_DIM + h) * 2 + 1];
        bbarT[(size_t)h * (2 * P_DIM) + 2 * p]     = (float)(cr * br - ci * bi);
        bbarT[(size_t)h * (2 * P_DIM) + 2 * p + 1] = (float)(cr * bi + ci * br);
    }
    for (int h = 0; h < H_DIM; ++h) {
        B2[(size_t)(2 * p) * H_DIM + h]     = c[((size_t)h * P_DIM + p) * 2];
        B2[(size_t)(2 * p + 1) * H_DIM + h] = -c[((size_t)h * P_DIM + p) * 2 + 1];
    }
}

// ---------------------------------------------------------------------------
// fp32 tiled GEMM: C[M x N] = A[M x K] * B[K x N], all row-major.
// 64x64 tile, BK=16, 256 threads, 4x4 microtile.
// Optional epilogue: C += D[n] * X[m*N + n]  (for ys = .. + d*x)
// ---------------------------------------------------------------------------
__global__ __launch_bounds__(256) void gemm64_f32(
    const float* __restrict__ A, const float* __restrict__ B,
    float* __restrict__ C, int M, int N, int K,
    const float* __restrict__ D, const float* __restrict__ X) {
    __shared__ float sA[16][68];
    __shared__ float sB[16][64];
    const int tid = threadIdx.x;
    const int tx = tid & 15, ty = tid >> 4;
    const int bm = blockIdx.y << 6, bn = blockIdx.x << 6;
    const int arow = tid >> 2;            // 0..63
    const int ak = (tid & 3) << 2;        // 0,4,8,12
    const int brow = tid >> 4;            // 0..15
    const int bc = (tid & 15) << 2;       // 0..60

    float acc[4][4] = {};
    const float* Ap = A + (size_t)(bm + arow) * K + ak;
    const float* Bp = B + (size_t)brow * N + bn + bc;

    for (int k0 = 0; k0 < K; k0 += 16) {
        float4 av = *(const float4*)(Ap + k0);
        float4 bv = *(const float4*)(Bp + (size_t)k0 * N);
        __syncthreads();
        sA[ak + 0][arow] = av.x;
        sA[ak + 1][arow] = av.y;
        sA[ak + 2][arow] = av.z;
        sA[ak + 3][arow] = av.w;
        *(float4*)&sB[brow][bc] = bv;
        __syncthreads();
#pragma unroll
        for (int k = 0; k < 16; ++k) {
            float4 a = *(const float4*)&sA[k][ty << 2];
            float4 b = *(const float4*)&sB[k][tx << 2];
            float ar[4] = {a.x, a.y, a.z, a.w};
            float br[4] = {b.x, b.y, b.z, b.w};
#pragma unroll
            for (int i = 0; i < 4; ++i)
#pragma unroll
                for (int j = 0; j < 4; ++j)
                    acc[i][j] = fmaf(ar[i], br[j], acc[i][j]);
        }
    }
#pragma unroll
    for (int i = 0; i < 4; ++i) {
        int row = bm + (ty << 2) + i;
        int col = bn + (tx << 2);
        float4 v = make_float4(acc[i][0], acc[i][1], acc[i][2], acc[i][3]);
        if (D != nullptr) {
            float4 xv = *(const float4*)(X + (size_t)row * N + col);
            v.x += D[col + 0] * xv.x;
            v.y += D[col + 1] * xv.y;
            v.z += D[col + 2] * xv.z;
            v.w += D[col + 3] * xv.w;
        }
        *(float4*)(C + (size_t)row * N + col) = v;
    }
}

// ---------------------------------------------------------------------------
// Scan phase A (f64 accum): per-chunk fold of (a=lbar, b=bx[t], c=mask[t])
// under the reset operator. 512 threads (one per p), one block per chunk.
// ---------------------------------------------------------------------------
__global__ __launch_bounds__(512) void scanA_kernel(
    const float* __restrict__ S, const float* __restrict__ mask,
    const double* __restrict__ lbar,
    double* __restrict__ cA, double* __restrict__ cS, float* __restrict__ cC) {
    int p = threadIdx.x;
    int blk = blockIdx.x;
    double lbr = lbar[2 * p], lbi = lbar[2 * p + 1];
    double Ar = 1., Ai = 0., Sr = 0., Si = 0.;
    float C = 0.f;
    const float2* S2 = (const float2*)S;
    int t0 = blk * CS;
    for (int t = t0; t < t0 + CS; ++t) {
        float m = mask[t];
        float2 bx = S2[(size_t)t * P_DIM + p];
        if (m != 0.f) {
            Ar = lbr; Ai = lbi; Sr = bx.x; Si = bx.y; C = 1.f;
        } else {
            double nAr = lbr * Ar - lbi * Ai;
            Ai = lbr * Ai + lbi * Ar; Ar = nAr;
            double nSr = lbr * Sr - lbi * Si + (double)bx.x;
            Si = lbr * Si + lbi * Sr + (double)bx.y; Sr = nSr;
        }
    }
    cA[(size_t)blk * 1024 + 2 * p] = Ar;
    cA[(size_t)blk * 1024 + 2 * p + 1] = Ai;
    cS[(size_t)blk * 1024 + 2 * p] = Sr;
    cS[(size_t)blk * 1024 + 2 * p + 1] = Si;
    cC[(size_t)blk * P_DIM + p] = C;
}

// ---------------------------------------------------------------------------
// Scan phase B (f64): sequential exclusive scan over chunk summaries.
// ---------------------------------------------------------------------------
__global__ __launch_bounds__(512) void scanB_kernel(
    const double* __restrict__ cA, const double* __restrict__ cS,
    const float* __restrict__ cC, const float* __restrict__ carry,
    double* __restrict__ prefix) {
    int p = threadIdx.x;
    double sr = (double)carry[2 * p], si = (double)carry[2 * p + 1];
    for (int i = 0; i < NB; ++i) {
        prefix[(size_t)i * 1024 + 2 * p] = sr;
        prefix[(size_t)i * 1024 + 2 * p + 1] = si;
        double Ar = cA[(size_t)i * 1024 + 2 * p];
        double Ai = cA[(size_t)i * 1024 + 2 * p + 1];
        double Sr = cS[(size_t)i * 1024 + 2 * p];
        double Si = cS[(size_t)i * 1024 + 2 * p + 1];
        float C = cC[(size_t)i * P_DIM + p];
        if (C != 0.f) {
            sr = Sr; si = Si;
        } else {
            double nr = Ar * sr - Ai * si + Sr;
            si = Ar * si + Ai * sr + Si;
            sr = nr;
        }
    }
}

// ---------------------------------------------------------------------------
// Scan phase C (f64): re-scan each chunk from its prefix, writing states
// (f32) in-place over bx. Last chunk writes final carry to d_out.
// carry_elems == 1024: interleaved re/im; == 512: real part only.
// ---------------------------------------------------------------------------
__global__ __launch_bounds__(512) void scanC_kernel(
    float* __restrict__ S, const float* __restrict__ mask,
    const double* __restrict__ lbar, const double* __restrict__ prefix,
    float* __restrict__ carry_out, int carry_elems) {
    int p = threadIdx.x;
    int blk = blockIdx.x;
    double lbr = lbar[2 * p], lbi = lbar[2 * p + 1];
    double sr = prefix[(size_t)blk * 1024 + 2 * p];
    double si = prefix[(size_t)blk * 1024 + 2 * p + 1];
    float2* S2 = (float2*)S;
    int t0 = blk * CS;
    for (int t = t0; t < t0 + CS; ++t) {
        float m = mask[t];
        float2 bx = S2[(size_t)t * P_DIM + p];
        if (m != 0.f) {
            sr = (double)bx.x; si = (double)bx.y;
        } else {
            double nr = lbr * sr - lbi * si + (double)bx.x;
            si = lbr * si + lbi * sr + (double)bx.y;
            sr = nr;
        }
        S2[(size_t)t * P_DIM + p] = make_float2((float)sr, (float)si);
    }
    if (blk == NB - 1) {
        if (carry_elems >= 1024) {
            carry_out[2 * p] = (float)sr;
            carry_out[2 * p + 1] = (float)si;
        } else {
            carry_out[p] = (float)sr;   // real part only
        }
    }
}

// ---------------------------------------------------------------------------
extern "C" void kernel_launch(void* const* d_in, const int* in_sizes, int n_in,
                              void* d_out, int out_size, void* d_ws, size_t ws_size,
                              hipStream_t stream) {
    const float* x           = (const float*)d_in[0];  // T*H
    const float* mask        = (const float*)d_in[1];  // T
    const float* carry       = (const float*)d_in[2];  // 1*P*2
    const float* lambda_real = (const float*)d_in[3];  // P
    const float* lambda_imag = (const float*)d_in[4];  // P
    const float* b           = (const float*)d_in[5];  // P*H*2
    const float* c           = (const float*)d_in[6];  // H*P*2
    const float* d           = (const float*)d_in[7];  // H
    const float* log_step    = (const float*)d_in[8];  // P*1

    float* out = (float*)d_out;
    char* ws = (char*)d_ws;

    // How many floats does the harness reserve for output 0 (the carry)?
    // complex64 counted as .size -> 512 (real-part compare);
    // viewed as float pairs -> 1024 (interleaved re/im).
    int carry_elems = out_size - T_LEN * H_DIM;
    if (carry_elems != 512 && carry_elems != 1024) carry_elems = 1024;
    float* ys_out = out + carry_elems;

    // workspace layout (doubles first for alignment)
    double* lbar   = (double*)ws;                        ws += 1024 * 8;
    double* cA     = (double*)ws;                        ws += (size_t)NB * 1024 * 8;
    double* cSb    = (double*)ws;                        ws += (size_t)NB * 1024 * 8;
    double* prefix = (double*)ws;                        ws += (size_t)NB * 1024 * 8;
    float* bbarT   = (float*)ws;                         ws += (size_t)H_DIM * 2 * P_DIM * 4;
    float* B2      = (float*)ws;                         ws += (size_t)2 * P_DIM * H_DIM * 4;
    float* S       = (float*)ws;                         ws += (size_t)T_LEN * 2 * P_DIM * 4;
    float* cC      = (float*)ws;                         ws += (size_t)NB * P_DIM * 4;

    // 1) precompute lbar (f64), bbarT, B2
    precompute_kernel<<<2, 256, 0, stream>>>(lambda_real, lambda_imag, b, c,
                                             log_step, lbar, bbarT, B2);

    // 2) GEMM1: S[T x 2P] = x[T x H] @ bbarT[H x 2P]
    {
        dim3 grid(2 * P_DIM / 64, T_LEN / 64);
        gemm64_f32<<<grid, 256, 0, stream>>>(x, bbarT, S, T_LEN, 2 * P_DIM,
                                             H_DIM, nullptr, nullptr);
    }

    // 3) chunked scan over T (f64 state arithmetic)
    scanA_kernel<<<NB, 512, 0, stream>>>(S, mask, lbar, cA, cSb, cC);
    scanB_kernel<<<1, 512, 0, stream>>>(cA, cSb, cC, carry, prefix);
    scanC_kernel<<<NB, 512, 0, stream>>>(S, mask, lbar, prefix, out, carry_elems);

    // 4) GEMM2: ys[T x H] = S[T x 2P] @ B2[2P x H] + d*x  -> ys_out
    {
        dim3 grid(H_DIM / 64, T_LEN / 64);
        gemm64_f32<<<grid, 256, 0, stream>>>(S, B2, ys_out, T_LEN, H_DIM,
                                             2 * P_DIM, d, x);
    }
}

// Round 4
// 421.510 us; speedup vs baseline: 1.4279x; 1.4279x over previous
//
#include <hip/hip_runtime.h>
#include <hip/hip_bf16.h>

#define T_LEN 8192
#define H_DIM 512
#define P_DIM 512
#define CS 32
#define NB (T_LEN / CS)   // 256 chunks

// ---------------------------------------------------------------------------
// P1: per-p lambda_bar (f64) and coef = (lbar-1)/lam (f64). One block.
// ---------------------------------------------------------------------------
__global__ __launch_bounds__(512) void precompute_p1(
    const float* __restrict__ lambda_real,
    const float* __restrict__ lambda_imag,
    const float* __restrict__ log_step,
    double* __restrict__ lbar,
    double* __restrict__ coef) {
    int p = threadIdx.x;
    double lr = fmin((double)lambda_real[p], -1e-4);
    double li = (double)lambda_imag[p];
    double step = exp((double)log_step[p]);          // STEP_RESCALE = 1
    double er = exp(lr * step);
    double ang = li * step;
    double lbr = er * cos(ang);
    double lbi = er * sin(ang);
    lbar[2 * p] = lbr;
    lbar[2 * p + 1] = lbi;
    double nr = lbr - 1.0, ni = lbi;
    double den = lr * lr + li * li;
    coef[2 * p]     = (nr * lr + ni * li) / den;
    coef[2 * p + 1] = (ni * lr - nr * li) / den;
}

// ---------------------------------------------------------------------------
// P2: fill bbarT[h][2p+c] = coef[p] * b~[p][h]   (f32, coalesced float2 write)
//     fill B2[2p][h] = c[h][p][0], B2[2p+1][h] = -c[h][p][1] (coalesced in h)
// 262144 threads; transposed reads ride L2 (b,c are 2 MB each).
// ---------------------------------------------------------------------------
__global__ __launch_bounds__(256) void precompute_p2(
    const float* __restrict__ b,
    const float* __restrict__ c,
    const double* __restrict__ coef,
    float* __restrict__ bbarT,
    float* __restrict__ B2) {
    int idx = blockIdx.x * 256 + threadIdx.x;        // 0 .. 262143
    // --- bbarT: p fastest for coalesced writes ---
    {
        int h = idx >> 9, p = idx & 511;
        double cr = coef[2 * p], ci = coef[2 * p + 1];
        float2 bv = *(const float2*)&b[((size_t)p * H_DIM + h) * 2];
        float2 o;
        o.x = (float)(cr * (double)bv.x - ci * (double)bv.y);
        o.y = (float)(cr * (double)bv.y + ci * (double)bv.x);
        *(float2*)&bbarT[(size_t)h * (2 * P_DIM) + 2 * p] = o;
    }
    // --- B2: h fastest for coalesced writes ---
    {
        int p = idx >> 9, h = idx & 511;
        float2 cv = *(const float2*)&c[((size_t)h * P_DIM + p) * 2];
        B2[(size_t)(2 * p) * H_DIM + h]     = cv.x;
        B2[(size_t)(2 * p + 1) * H_DIM + h] = -cv.y;
    }
}

// ---------------------------------------------------------------------------
// fp32 tiled GEMM: C[M x N] = A[M x K] * B[K x N], all row-major.
// 64x64 tile, BK=16, 256 threads, 4x4 microtile.
// Optional epilogue: C += D[n] * X[m*N + n]  (for ys = .. + d*x)
// ---------------------------------------------------------------------------
__global__ __launch_bounds__(256) void gemm64_f32(
    const float* __restrict__ A, const float* __restrict__ B,
    float* __restrict__ C, int M, int N, int K,
    const float* __restrict__ D, const float* __restrict__ X) {
    __shared__ float sA[16][68];
    __shared__ float sB[16][64];
    const int tid = threadIdx.x;
    const int tx = tid & 15, ty = tid >> 4;
    const int bm = blockIdx.y << 6, bn = blockIdx.x << 6;
    const int arow = tid >> 2;            // 0..63
    const int ak = (tid & 3) << 2;        // 0,4,8,12
    const int brow = tid >> 4;            // 0..15
    const int bc = (tid & 15) << 2;       // 0..60

    float acc[4][4] = {};
    const float* Ap = A + (size_t)(bm + arow) * K + ak;
    const float* Bp = B + (size_t)brow * N + bn + bc;

    for (int k0 = 0; k0 < K; k0 += 16) {
        float4 av = *(const float4*)(Ap + k0);
        float4 bv = *(const float4*)(Bp + (size_t)k0 * N);
        __syncthreads();
        sA[ak + 0][arow] = av.x;
        sA[ak + 1][arow] = av.y;
        sA[ak + 2][arow] = av.z;
        sA[ak + 3][arow] = av.w;
        *(float4*)&sB[brow][bc] = bv;
        __syncthreads();
#pragma unroll
        for (int k = 0; k < 16; ++k) {
            float4 a = *(const float4*)&sA[k][ty << 2];
            float4 b = *(const float4*)&sB[k][tx << 2];
            float ar[4] = {a.x, a.y, a.z, a.w};
            float br[4] = {b.x, b.y, b.z, b.w};
#pragma unroll
            for (int i = 0; i < 4; ++i)
#pragma unroll
                for (int j = 0; j < 4; ++j)
                    acc[i][j] = fmaf(ar[i], br[j], acc[i][j]);
        }
    }
#pragma unroll
    for (int i = 0; i < 4; ++i) {
        int row = bm + (ty << 2) + i;
        int col = bn + (tx << 2);
        float4 v = make_float4(acc[i][0], acc[i][1], acc[i][2], acc[i][3]);
        if (D != nullptr) {
            float4 xv = *(const float4*)(X + (size_t)row * N + col);
            v.x += D[col + 0] * xv.x;
            v.y += D[col + 1] * xv.y;
            v.z += D[col + 2] * xv.z;
            v.w += D[col + 3] * xv.w;
        }
        *(float4*)(C + (size_t)row * N + col) = v;
    }
}

// ---------------------------------------------------------------------------
// Scan phase A (f64 accum): per-chunk fold of (a=lbar, b=bx[t], c=mask[t])
// under the reset operator. 512 threads (one per p), one block per chunk.
// ---------------------------------------------------------------------------
__global__ __launch_bounds__(512) void scanA_kernel(
    const float* __restrict__ S, const float* __restrict__ mask,
    const double* __restrict__ lbar,
    double* __restrict__ cA, double* __restrict__ cS, float* __restrict__ cC) {
    int p = threadIdx.x;
    int blk = blockIdx.x;
    double lbr = lbar[2 * p], lbi = lbar[2 * p + 1];
    double Ar = 1., Ai = 0., Sr = 0., Si = 0.;
    float C = 0.f;
    const float2* S2 = (const float2*)S;
    int t0 = blk * CS;
    for (int t = t0; t < t0 + CS; ++t) {
        float m = mask[t];
        float2 bx = S2[(size_t)t * P_DIM + p];
        if (m != 0.f) {
            Ar = lbr; Ai = lbi; Sr = bx.x; Si = bx.y; C = 1.f;
        } else {
            double nAr = lbr * Ar - lbi * Ai;
            Ai = lbr * Ai + lbi * Ar; Ar = nAr;
            double nSr = lbr * Sr - lbi * Si + (double)bx.x;
            Si = lbr * Si + lbi * Sr + (double)bx.y; Sr = nSr;
        }
    }
    cA[(size_t)blk * 1024 + 2 * p] = Ar;
    cA[(size_t)blk * 1024 + 2 * p + 1] = Ai;
    cS[(size_t)blk * 1024 + 2 * p] = Sr;
    cS[(size_t)blk * 1024 + 2 * p + 1] = Si;
    cC[(size_t)blk * P_DIM + p] = C;
}

// ---------------------------------------------------------------------------
// Scan phase B (f64): sequential exclusive scan over chunk summaries.
// ---------------------------------------------------------------------------
__global__ __launch_bounds__(512) void scanB_kernel(
    const double* __restrict__ cA, const double* __restrict__ cS,
    const float* __restrict__ cC, const float* __restrict__ carry,
    double* __restrict__ prefix) {
    int p = threadIdx.x;
    double sr = (double)carry[2 * p], si = (double)carry[2 * p + 1];
    for (int i = 0; i < NB; ++i) {
        prefix[(size_t)i * 1024 + 2 * p] = sr;
        prefix[(size_t)i * 1024 + 2 * p + 1] = si;
        double Ar = cA[(size_t)i * 1024 + 2 * p];
        double Ai = cA[(size_t)i * 1024 + 2 * p + 1];
        double Sr = cS[(size_t)i * 1024 + 2 * p];
        double Si = cS[(size_t)i * 1024 + 2 * p + 1];
        float C = cC[(size_t)i * P_DIM + p];
        if (C != 0.f) {
            sr = Sr; si = Si;
        } else {
            double nr = Ar * sr - Ai * si + Sr;
            si = Ar * si + Ai * sr + Si;
            sr = nr;
        }
    }
}

// ---------------------------------------------------------------------------
// Scan phase C (f64): re-scan each chunk from its prefix, writing states
// (f32) in-place over bx. Last chunk writes final carry to d_out.
// carry_elems == 1024: interleaved re/im; == 512: real part only.
// ---------------------------------------------------------------------------
__global__ __launch_bounds__(512) void scanC_kernel(
    float* __restrict__ S, const float* __restrict__ mask,
    const double* __restrict__ lbar, const double* __restrict__ prefix,
    float* __restrict__ carry_out, int carry_elems) {
    int p = threadIdx.x;
    int blk = blockIdx.x;
    double lbr = lbar[2 * p], lbi = lbar[2 * p + 1];
    double sr = prefix[(size_t)blk * 1024 + 2 * p];
    double si = prefix[(size_t)blk * 1024 + 2 * p + 1];
    float2* S2 = (float2*)S;
    int t0 = blk * CS;
    for (int t = t0; t < t0 + CS; ++t) {
        float m = mask[t];
        float2 bx = S2[(size_t)t * P_DIM + p];
        if (m != 0.f) {
            sr = (double)bx.x; si = (double)bx.y;
        } else {
            double nr = lbr * sr - lbi * si + (double)bx.x;
            si = lbr * si + lbi * sr + (double)bx.y;
            sr = nr;
        }
        S2[(size_t)t * P_DIM + p] = make_float2((float)sr, (float)si);
    }
    if (blk == NB - 1) {
        if (carry_elems >= 1024) {
            carry_out[2 * p] = (float)sr;
            carry_out[2 * p + 1] = (float)si;
        } else {
            carry_out[p] = (float)sr;   // real part only
        }
    }
}

// ---------------------------------------------------------------------------
extern "C" void kernel_launch(void* const* d_in, const int* in_sizes, int n_in,
                              void* d_out, int out_size, void* d_ws, size_t ws_size,
                              hipStream_t stream) {
    const float* x           = (const float*)d_in[0];  // T*H
    const float* mask        = (const float*)d_in[1];  // T
    const float* carry       = (const float*)d_in[2];  // 1*P*2
    const float* lambda_real = (const float*)d_in[3];  // P
    const float* lambda_imag = (const float*)d_in[4];  // P
    const float* b           = (const float*)d_in[5];  // P*H*2
    const float* c           = (const float*)d_in[6];  // H*P*2
    const float* d           = (const float*)d_in[7];  // H
    const float* log_step    = (const float*)d_in[8];  // P*1

    float* out = (float*)d_out;
    char* ws = (char*)d_ws;

    int carry_elems = out_size - T_LEN * H_DIM;
    if (carry_elems != 512 && carry_elems != 1024) carry_elems = 1024;
    float* ys_out = out + carry_elems;

    // workspace layout (doubles first for alignment)
    double* lbar   = (double*)ws;                        ws += 1024 * 8;
    double* coef   = (double*)ws;                        ws += 1024 * 8;
    double* cA     = (double*)ws;                        ws += (size_t)NB * 1024 * 8;
    double* cSb    = (double*)ws;                        ws += (size_t)NB * 1024 * 8;
    double* prefix = (double*)ws;                        ws += (size_t)NB * 1024 * 8;
    float* bbarT   = (float*)ws;                         ws += (size_t)H_DIM * 2 * P_DIM * 4;
    float* B2      = (float*)ws;                         ws += (size_t)2 * P_DIM * H_DIM * 4;
    float* S       = (float*)ws;                         ws += (size_t)T_LEN * 2 * P_DIM * 4;
    float* cC      = (float*)ws;                         ws += (size_t)NB * P_DIM * 4;

    // 1) precompute: P1 (per-p, f64) then P2 (parallel fill)
    precompute_p1<<<1, 512, 0, stream>>>(lambda_real, lambda_imag, log_step,
                                         lbar, coef);
    precompute_p2<<<(P_DIM * H_DIM) / 256, 256, 0, stream>>>(b, c, coef,
                                                             bbarT, B2);

    // 2) GEMM1: S[T x 2P] = x[T x H] @ bbarT[H x 2P]
    {
        dim3 grid(2 * P_DIM / 64, T_LEN / 64);
        gemm64_f32<<<grid, 256, 0, stream>>>(x, bbarT, S, T_LEN, 2 * P_DIM,
                                             H_DIM, nullptr, nullptr);
    }

    // 3) chunked scan over T (f64 state arithmetic)
    scanA_kernel<<<NB, 512, 0, stream>>>(S, mask, lbar, cA, cSb, cC);
    scanB_kernel<<<1, 512, 0, stream>>>(cA, cSb, cC, carry, prefix);
    scanC_kernel<<<NB, 512, 0, stream>>>(S, mask, lbar, prefix, out, carry_elems);

    // 4) GEMM2: ys[T x H] = S[T x 2P] @ B2[2P x H] + d*x  -> ys_out
    {
        dim3 grid(H_DIM / 64, T_LEN / 64);
        gemm64_f32<<<grid, 256, 0, stream>>>(S, B2, ys_out, T_LEN, H_DIM,
                                             2 * P_DIM, d, x);
    }
}

// Round 5
// 294.565 us; speedup vs baseline: 2.0433x; 1.4310x over previous
//
#include <hip/hip_runtime.h>
#include <hip/hip_bf16.h>

#define T_LEN 8192
#define H_DIM 512
#define P_DIM 512
#define CS 32
#define NB (T_LEN / CS)   // 256 chunks

// ---------------------------------------------------------------------------
// P1: per-p lambda_bar (f64) and coef = (lbar-1)/lam (f64). One block.
// ---------------------------------------------------------------------------
__global__ __launch_bounds__(512) void precompute_p1(
    const float* __restrict__ lambda_real,
    const float* __restrict__ lambda_imag,
    const float* __restrict__ log_step,
    double* __restrict__ lbar,
    double* __restrict__ coef) {
    int p = threadIdx.x;
    double lr = fmin((double)lambda_real[p], -1e-4);
    double li = (double)lambda_imag[p];
    double step = exp((double)log_step[p]);          // STEP_RESCALE = 1
    double er = exp(lr * step);
    double ang = li * step;
    double lbr = er * cos(ang);
    double lbi = er * sin(ang);
    lbar[2 * p] = lbr;
    lbar[2 * p + 1] = lbi;
    double nr = lbr - 1.0, ni = lbi;
    double den = lr * lr + li * li;
    coef[2 * p]     = (nr * lr + ni * li) / den;
    coef[2 * p + 1] = (ni * lr - nr * li) / den;
}

// ---------------------------------------------------------------------------
// P2: fill bbarT[h][2p+c] = coef[p] * b~[p][h]   (f32, coalesced float2 write)
//     fill B2[2p][h] = c[h][p][0], B2[2p+1][h] = -c[h][p][1] (coalesced in h)
// ---------------------------------------------------------------------------
__global__ __launch_bounds__(256) void precompute_p2(
    const float* __restrict__ b,
    const float* __restrict__ c,
    const double* __restrict__ coef,
    float* __restrict__ bbarT,
    float* __restrict__ B2) {
    int idx = blockIdx.x * 256 + threadIdx.x;        // 0 .. 262143
    {
        int h = idx >> 9, p = idx & 511;
        double cr = coef[2 * p], ci = coef[2 * p + 1];
        float2 bv = *(const float2*)&b[((size_t)p * H_DIM + h) * 2];
        float2 o;
        o.x = (float)(cr * (double)bv.x - ci * (double)bv.y);
        o.y = (float)(cr * (double)bv.y + ci * (double)bv.x);
        *(float2*)&bbarT[(size_t)h * (2 * P_DIM) + 2 * p] = o;
    }
    {
        int p = idx >> 9, h = idx & 511;
        float2 cv = *(const float2*)&c[((size_t)h * P_DIM + p) * 2];
        B2[(size_t)(2 * p) * H_DIM + h]     = cv.x;
        B2[(size_t)(2 * p + 1) * H_DIM + h] = -cv.y;
    }
}

// ---------------------------------------------------------------------------
// fp32 tiled GEMM: C[M x N] = A[M x K] * B[K x N], all row-major.
// 64x64 tile, BK=16, 256 threads, 4x4 microtile.
// Optional epilogue: C += D[n] * X[m*N + n]
// ---------------------------------------------------------------------------
__global__ __launch_bounds__(256) void gemm64_f32(
    const float* __restrict__ A, const float* __restrict__ B,
    float* __restrict__ C, int M, int N, int K,
    const float* __restrict__ D, const float* __restrict__ X) {
    __shared__ float sA[16][68];
    __shared__ float sB[16][64];
    const int tid = threadIdx.x;
    const int tx = tid & 15, ty = tid >> 4;
    const int bm = blockIdx.y << 6, bn = blockIdx.x << 6;
    const int arow = tid >> 2;            // 0..63
    const int ak = (tid & 3) << 2;        // 0,4,8,12
    const int brow = tid >> 4;            // 0..15
    const int bc = (tid & 15) << 2;       // 0..60

    float acc[4][4] = {};
    const float* Ap = A + (size_t)(bm + arow) * K + ak;
    const float* Bp = B + (size_t)brow * N + bn + bc;

    for (int k0 = 0; k0 < K; k0 += 16) {
        float4 av = *(const float4*)(Ap + k0);
        float4 bv = *(const float4*)(Bp + (size_t)k0 * N);
        __syncthreads();
        sA[ak + 0][arow] = av.x;
        sA[ak + 1][arow] = av.y;
        sA[ak + 2][arow] = av.z;
        sA[ak + 3][arow] = av.w;
        *(float4*)&sB[brow][bc] = bv;
        __syncthreads();
#pragma unroll
        for (int k = 0; k < 16; ++k) {
            float4 a = *(const float4*)&sA[k][ty << 2];
            float4 b = *(const float4*)&sB[k][tx << 2];
            float ar[4] = {a.x, a.y, a.z, a.w};
            float br[4] = {b.x, b.y, b.z, b.w};
#pragma unroll
            for (int i = 0; i < 4; ++i)
#pragma unroll
                for (int j = 0; j < 4; ++j)
                    acc[i][j] = fmaf(ar[i], br[j], acc[i][j]);
        }
    }
#pragma unroll
    for (int i = 0; i < 4; ++i) {
        int row = bm + (ty << 2) + i;
        int col = bn + (tx << 2);
        float4 v = make_float4(acc[i][0], acc[i][1], acc[i][2], acc[i][3]);
        if (D != nullptr) {
            float4 xv = *(const float4*)(X + (size_t)row * N + col);
            v.x += D[col + 0] * xv.x;
            v.y += D[col + 1] * xv.y;
            v.z += D[col + 2] * xv.z;
            v.w += D[col + 3] * xv.w;
        }
        *(float4*)(C + (size_t)row * N + col) = v;
    }
}

// ---------------------------------------------------------------------------
// Scan phase A (f64 accum): per-chunk fold of (a=lbar, b=bx[t], c=mask[t])
// under the reset operator. 512 threads (one per p), one block per chunk.
// ---------------------------------------------------------------------------
__global__ __launch_bounds__(512) void scanA_kernel(
    const float* __restrict__ S, const float* __restrict__ mask,
    const double* __restrict__ lbar,
    double* __restrict__ cA, double* __restrict__ cS, float* __restrict__ cC) {
    int p = threadIdx.x;
    int blk = blockIdx.x;
    double lbr = lbar[2 * p], lbi = lbar[2 * p + 1];
    double Ar = 1., Ai = 0., Sr = 0., Si = 0.;
    float C = 0.f;
    const float2* S2 = (const float2*)S;
    int t0 = blk * CS;
    for (int t = t0; t < t0 + CS; ++t) {
        float m = mask[t];
        float2 bx = S2[(size_t)t * P_DIM + p];
        if (m != 0.f) {
            Ar = lbr; Ai = lbi; Sr = bx.x; Si = bx.y; C = 1.f;
        } else {
            double nAr = lbr * Ar - lbi * Ai;
            Ai = lbr * Ai + lbi * Ar; Ar = nAr;
            double nSr = lbr * Sr - lbi * Si + (double)bx.x;
            Si = lbr * Si + lbi * Sr + (double)bx.y; Sr = nSr;
        }
    }
    cA[(size_t)blk * 1024 + 2 * p] = Ar;
    cA[(size_t)blk * 1024 + 2 * p + 1] = Ai;
    cS[(size_t)blk * 1024 + 2 * p] = Sr;
    cS[(size_t)blk * 1024 + 2 * p + 1] = Si;
    cC[(size_t)blk * P_DIM + p] = C;
}

// ---------------------------------------------------------------------------
// Scan phase B (f64, PARALLEL): one block per p (512 blocks), 256 threads
// (one per chunk). Kogge-Stone inclusive scan over (A,S,C) triples in LDS,
// then apply initial carry to produce the exclusive prefix per chunk.
// ---------------------------------------------------------------------------
__global__ __launch_bounds__(256) void scanB_kernel(
    const double* __restrict__ cA, const double* __restrict__ cS,
    const float* __restrict__ cC, const float* __restrict__ carry,
    double* __restrict__ prefix) {
    int p = blockIdx.x;      // 0..511
    int i = threadIdx.x;     // chunk 0..255
    __shared__ double sAr[NB], sAi[NB], sSr[NB], sSi[NB];
    __shared__ float sC[NB];

    double Ar = cA[(size_t)i * 1024 + 2 * p];
    double Ai = cA[(size_t)i * 1024 + 2 * p + 1];
    double Sr = cS[(size_t)i * 1024 + 2 * p];
    double Si = cS[(size_t)i * 1024 + 2 * p + 1];
    float  C  = cC[(size_t)i * P_DIM + p];
    sAr[i] = Ar; sAi[i] = Ai; sSr[i] = Sr; sSi[i] = Si; sC[i] = C;
    __syncthreads();

    // Kogge-Stone: new[i] = compose(old[i-step] /*left*/, old[i] /*right*/)
    for (int step = 1; step < NB; step <<= 1) {
        double pAr = 0, pAi = 0, pSr = 0, pSi = 0; float pC = 0;
        if (i >= step) {
            pAr = sAr[i - step]; pAi = sAi[i - step];
            pSr = sSr[i - step]; pSi = sSi[i - step]; pC = sC[i - step];
        }
        __syncthreads();
        if (i >= step && C == 0.f) {
            // right has no reset: fold left through
            double nAr = Ar * pAr - Ai * pAi;
            double nAi = Ar * pAi + Ai * pAr;
            double nSr = Ar * pSr - Ai * pSi + Sr;
            double nSi = Ar * pSi + Ai * pSr + Si;
            Ar = nAr; Ai = nAi; Sr = nSr; Si = nSi; C = pC;
        }
        // right has reset (C==1): keep own triple
        sAr[i] = Ar; sAi[i] = Ai; sSr[i] = Sr; sSi[i] = Si; sC[i] = C;
        __syncthreads();
    }

    // exclusive prefix: state entering chunk i
    double c0r = (double)carry[2 * p], c0i = (double)carry[2 * p + 1];
    double pr, pi_;
    if (i == 0) {
        pr = c0r; pi_ = c0i;
    } else {
        double Lr = sAr[i - 1], Li = sAi[i - 1];
        double Tr = sSr[i - 1], Ti = sSi[i - 1];
        float  LC = sC[i - 1];
        if (LC != 0.f) { pr = Tr; pi_ = Ti; }
        else {
            pr  = Lr * c0r - Li * c0i + Tr;
            pi_ = Lr * c0i + Li * c0r + Ti;
        }
    }
    prefix[(size_t)i * 1024 + 2 * p]     = pr;
    prefix[(size_t)i * 1024 + 2 * p + 1] = pi_;
}

// ---------------------------------------------------------------------------
// Scan phase C (f64): re-scan each chunk from its prefix, writing states
// (f32) in-place over bx. Last chunk writes final carry to d_out.
// ---------------------------------------------------------------------------
__global__ __launch_bounds__(512) void scanC_kernel(
    float* __restrict__ S, const float* __restrict__ mask,
    const double* __restrict__ lbar, const double* __restrict__ prefix,
    float* __restrict__ carry_out, int carry_elems) {
    int p = threadIdx.x;
    int blk = blockIdx.x;
    double lbr = lbar[2 * p], lbi = lbar[2 * p + 1];
    double sr = prefix[(size_t)blk * 1024 + 2 * p];
    double si = prefix[(size_t)blk * 1024 + 2 * p + 1];
    float2* S2 = (float2*)S;
    int t0 = blk * CS;
    for (int t = t0; t < t0 + CS; ++t) {
        float m = mask[t];
        float2 bx = S2[(size_t)t * P_DIM + p];
        if (m != 0.f) {
            sr = (double)bx.x; si = (double)bx.y;
        } else {
            double nr = lbr * sr - lbi * si + (double)bx.x;
            si = lbr * si + lbi * sr + (double)bx.y;
            sr = nr;
        }
        S2[(size_t)t * P_DIM + p] = make_float2((float)sr, (float)si);
    }
    if (blk == NB - 1) {
        if (carry_elems >= 1024) {
            carry_out[2 * p] = (float)sr;
            carry_out[2 * p + 1] = (float)si;
        } else {
            carry_out[p] = (float)sr;   // real part only
        }
    }
}

// ---------------------------------------------------------------------------
extern "C" void kernel_launch(void* const* d_in, const int* in_sizes, int n_in,
                              void* d_out, int out_size, void* d_ws, size_t ws_size,
                              hipStream_t stream) {
    const float* x           = (const float*)d_in[0];  // T*H
    const float* mask        = (const float*)d_in[1];  // T
    const float* carry       = (const float*)d_in[2];  // 1*P*2
    const float* lambda_real = (const float*)d_in[3];  // P
    const float* lambda_imag = (const float*)d_in[4];  // P
    const float* b           = (const float*)d_in[5];  // P*H*2
    const float* c           = (const float*)d_in[6];  // H*P*2
    const float* d           = (const float*)d_in[7];  // H
    const float* log_step    = (const float*)d_in[8];  // P*1

    float* out = (float*)d_out;
    char* ws = (char*)d_ws;

    int carry_elems = out_size - T_LEN * H_DIM;
    if (carry_elems != 512 && carry_elems != 1024) carry_elems = 1024;
    float* ys_out = out + carry_elems;

    // workspace layout (doubles first for alignment)
    double* lbar   = (double*)ws;                        ws += 1024 * 8;
    double* coef   = (double*)ws;                        ws += 1024 * 8;
    double* cA     = (double*)ws;                        ws += (size_t)NB * 1024 * 8;
    double* cSb    = (double*)ws;                        ws += (size_t)NB * 1024 * 8;
    double* prefix = (double*)ws;                        ws += (size_t)NB * 1024 * 8;
    float* bbarT   = (float*)ws;                         ws += (size_t)H_DIM * 2 * P_DIM * 4;
    float* B2      = (float*)ws;                         ws += (size_t)2 * P_DIM * H_DIM * 4;
    float* S       = (float*)ws;                         ws += (size_t)T_LEN * 2 * P_DIM * 4;
    float* cC      = (float*)ws;                         ws += (size_t)NB * P_DIM * 4;

    // 1) precompute
    precompute_p1<<<1, 512, 0, stream>>>(lambda_real, lambda_imag, log_step,
                                         lbar, coef);
    precompute_p2<<<(P_DIM * H_DIM) / 256, 256, 0, stream>>>(b, c, coef,
                                                             bbarT, B2);

    // 2) GEMM1: S[T x 2P] = x[T x H] @ bbarT[H x 2P]
    {
        dim3 grid(2 * P_DIM / 64, T_LEN / 64);
        gemm64_f32<<<grid, 256, 0, stream>>>(x, bbarT, S, T_LEN, 2 * P_DIM,
                                             H_DIM, nullptr, nullptr);
    }

    // 3) chunked scan over T (f64 state arithmetic)
    scanA_kernel<<<NB, 512, 0, stream>>>(S, mask, lbar, cA, cSb, cC);
    scanB_kernel<<<P_DIM, NB, 0, stream>>>(cA, cSb, cC, carry, prefix);
    scanC_kernel<<<NB, 512, 0, stream>>>(S, mask, lbar, prefix, out, carry_elems);

    // 4) GEMM2: ys[T x H] = S[T x 2P] @ B2[2P x H] + d*x  -> ys_out
    {
        dim3 grid(H_DIM / 64, T_LEN / 64);
        gemm64_f32<<<grid, 256, 0, stream>>>(S, B2, ys_out, T_LEN, H_DIM,
                                             2 * P_DIM, d, x);
    }
}

// Round 6
// 122.057 us; speedup vs baseline: 4.9313x; 2.4133x over previous
//
#include <hip/hip_runtime.h>
#include <hip/hip_bf16.h>

#define T_LEN 8192
#define H_DIM 512
#define P_DIM 512
#define CS 32
#define NB (T_LEN / CS)   // 256 chunks

typedef __attribute__((ext_vector_type(8))) __bf16 bf16x8;
typedef __attribute__((ext_vector_type(4))) float f32x4;

__device__ __forceinline__ unsigned short f2bf(float f) {
    __bf16 h = (__bf16)f;
    return __builtin_bit_cast(unsigned short, h);
}
__device__ __forceinline__ float bf2f(unsigned short u) {
    unsigned v = ((unsigned)u) << 16;
    return __builtin_bit_cast(float, v);
}

__device__ __forceinline__ void gload_lds16(void* g, void* l) {
    __builtin_amdgcn_global_load_lds(
        (__attribute__((address_space(1))) unsigned*)g,
        (__attribute__((address_space(3))) unsigned*)l, 16, 0, 0);
}

// ---------------------------------------------------------------------------
// P1: per-p lambda_bar (f64) and coef = (lbar-1)/lam (f64). One block.
// ---------------------------------------------------------------------------
__global__ __launch_bounds__(512) void precompute_p1(
    const float* __restrict__ lambda_real,
    const float* __restrict__ lambda_imag,
    const float* __restrict__ log_step,
    double* __restrict__ lbar,
    double* __restrict__ coef) {
    int p = threadIdx.x;
    double lr = fmin((double)lambda_real[p], -1e-4);
    double li = (double)lambda_imag[p];
    double step = exp((double)log_step[p]);          // STEP_RESCALE = 1
    double er = exp(lr * step);
    double ang = li * step;
    double lbr = er * cos(ang);
    double lbi = er * sin(ang);
    lbar[2 * p] = lbr;
    lbar[2 * p + 1] = lbi;
    double nr = lbr - 1.0, ni = lbi;
    double den = lr * lr + li * li;
    coef[2 * p]     = (nr * lr + ni * li) / den;
    coef[2 * p + 1] = (ni * lr - nr * li) / den;
}

// ---------------------------------------------------------------------------
// conv_x: x (f32) -> x_hi, x_lo (bf16 split). 2 floats per thread.
// ---------------------------------------------------------------------------
__global__ __launch_bounds__(256) void conv_x_kernel(
    const float* __restrict__ x,
    unsigned short* __restrict__ xhi, unsigned short* __restrict__ xlo) {
    int idx = blockIdx.x * 256 + threadIdx.x;        // 0 .. T*H/2-1
    float2 v = ((const float2*)x)[idx];
    ushort2 h, l;
    h.x = f2bf(v.x); l.x = f2bf(v.x - bf2f(h.x));
    h.y = f2bf(v.y); l.y = f2bf(v.y - bf2f(h.y));
    ((ushort2*)xhi)[idx] = h;
    ((ushort2*)xlo)[idx] = l;
}

// ---------------------------------------------------------------------------
// fillB: Bt1[n=2p(+1)][k=h] = Re/Im(coef[p]*b~[p][h])  (bf16 hi/lo)
//        Bt2[n=h][k=2p(+1)] = c[h][p][0] / -c[h][p][1] (bf16 hi/lo)
// ---------------------------------------------------------------------------
__global__ __launch_bounds__(256) void fillB_kernel(
    const float* __restrict__ b, const float* __restrict__ c,
    const double* __restrict__ coef,
    unsigned short* __restrict__ Bt1hi, unsigned short* __restrict__ Bt1lo,
    unsigned short* __restrict__ Bt2hi, unsigned short* __restrict__ Bt2lo) {
    int idx = blockIdx.x * 256 + threadIdx.x;        // 0 .. 262143
    {   // Bt1: rows 2p,2p+1 (stride H_DIM), coalesced in h
        int p = idx >> 9, h = idx & 511;
        double cr = coef[2 * p], ci = coef[2 * p + 1];
        float2 bv = ((const float2*)b)[(size_t)p * H_DIM + h];
        float re = (float)(cr * (double)bv.x - ci * (double)bv.y);
        float im = (float)(cr * (double)bv.y + ci * (double)bv.x);
        unsigned short rh = f2bf(re), ih = f2bf(im);
        Bt1hi[(size_t)(2 * p) * H_DIM + h]     = rh;
        Bt1lo[(size_t)(2 * p) * H_DIM + h]     = f2bf(re - bf2f(rh));
        Bt1hi[(size_t)(2 * p + 1) * H_DIM + h] = ih;
        Bt1lo[(size_t)(2 * p + 1) * H_DIM + h] = f2bf(im - bf2f(ih));
    }
    {   // Bt2: row h (stride 2P), cols 2p,2p+1 -> ushort2, coalesced in p
        int h = idx >> 9, p = idx & 511;
        float2 cv = ((const float2*)c)[(size_t)h * P_DIM + p];
        float re = cv.x, im = -cv.y;
        ushort2 hi, lo;
        hi.x = f2bf(re); lo.x = f2bf(re - bf2f(hi.x));
        hi.y = f2bf(im); lo.y = f2bf(im - bf2f(hi.y));
        ((ushort2*)Bt2hi)[(size_t)h * P_DIM + p] = hi;
        ((ushort2*)Bt2lo)[(size_t)h * P_DIM + p] = lo;
    }
}

// ---------------------------------------------------------------------------
// Split-bf16 MFMA GEMM: C[M x N] = (Ahi+Alo)[M x K] * (Bhi+Blo)^T-staged
// B given TRANSPOSED: Bt[n][k]. 128x128 tile, BK=32, 256 thr = 4 waves (2x2).
// Each wave: 64x64 = 4x4 MFMA tiles of 16x16, 3 passes (hh, hl, lh).
// MODE 0: write C as bf16 hi/lo split (Cout0/Cout1).
// MODE 1: write f32 C + D[col]*X[row][col] into Cout0.
// LDS tiles [128 rows][32 shorts=64B], chunk-swizzled: pos = c ^ ((row>>1)&3).
// ---------------------------------------------------------------------------
template <int MODE>
__global__ __launch_bounds__(256) void gemm_mfma_split(
    const unsigned short* __restrict__ Ahi, const unsigned short* __restrict__ Alo,
    int lda,
    const unsigned short* __restrict__ Bthi, const unsigned short* __restrict__ Btlo,
    int ldb,
    void* __restrict__ Cout0, void* __restrict__ Cout1, int ldc, int K,
    const float* __restrict__ Dvec, const float* __restrict__ X) {
    __shared__ __align__(16) unsigned short lds[2][4][128 * 32];
    const int tid = threadIdx.x;
    const int lane = tid & 63, wid = tid >> 6;
    const int wm = wid >> 1, wn = wid & 1;
    const int bm = blockIdx.y * 128, bn = blockIdx.x * 128;

    // staging source for this wave: tile wid of {Ahi, Alo, Bthi, Btlo}
    const unsigned short* ssrc;
    int srow0, sld;
    if (wid == 0)      { ssrc = Ahi;  srow0 = bm; sld = lda; }
    else if (wid == 1) { ssrc = Alo;  srow0 = bm; sld = lda; }
    else if (wid == 2) { ssrc = Bthi; srow0 = bn; sld = ldb; }
    else               { ssrc = Btlo; srow0 = bn; sld = ldb; }

    f32x4 acc[4][4];
#pragma unroll
    for (int i = 0; i < 4; ++i)
#pragma unroll
        for (int j = 0; j < 4; ++j) acc[i][j] = (f32x4)(0.0f);

    // stage one [128][32] bf16 tile (8 KB) = 8 x 1024B instructions
    auto stage = [&](int buf, int k0) {
        unsigned short* base = &lds[buf][wid][0];
#pragma unroll
        for (int s = 0; s < 8; ++s) {
            int r = s * 16 + (lane >> 2);
            int cg = (lane & 3) ^ ((r >> 1) & 3);
            void* g = (void*)((const char*)(ssrc + (size_t)(srow0 + r) * sld + k0)
                              + cg * 16);
            gload_lds16(g, (void*)((char*)base + s * 1024));
        }
    };

    stage(0, 0);
    __syncthreads();   // drains vmcnt

    const int nk = K / 32;
    for (int t = 0; t < nk; ++t) {
        int cur = t & 1;
        if (t + 1 < nk) stage(cur ^ 1, (t + 1) * 32);

        bf16x8 ah[4], al[4], bh[4], bl[4];
#pragma unroll
        for (int i = 0; i < 4; ++i) {
            int rA = wm * 64 + i * 16 + (lane & 15);
            int byA = rA * 64 + ((((lane >> 4)) ^ ((rA >> 1) & 3)) << 4);
            ah[i] = *(const bf16x8*)((const char*)&lds[cur][0][0] + byA);
            al[i] = *(const bf16x8*)((const char*)&lds[cur][1][0] + byA);
            int rB = wn * 64 + i * 16 + (lane & 15);
            int byB = rB * 64 + ((((lane >> 4)) ^ ((rB >> 1) & 3)) << 4);
            bh[i] = *(const bf16x8*)((const char*)&lds[cur][2][0] + byB);
            bl[i] = *(const bf16x8*)((const char*)&lds[cur][3][0] + byB);
        }
#pragma unroll
        for (int i = 0; i < 4; ++i)
#pragma unroll
            for (int j = 0; j < 4; ++j) {
                acc[i][j] = __builtin_amdgcn_mfma_f32_16x16x32_bf16(
                    ah[i], bh[j], acc[i][j], 0, 0, 0);
                acc[i][j] = __builtin_amdgcn_mfma_f32_16x16x32_bf16(
                    ah[i], bl[j], acc[i][j], 0, 0, 0);
                acc[i][j] = __builtin_amdgcn_mfma_f32_16x16x32_bf16(
                    al[i], bh[j], acc[i][j], 0, 0, 0);
            }
        __syncthreads();
    }

    // epilogue. C/D map (verified m89/m91): col = lane&15, row = 4*(lane>>4)+reg
#pragma unroll
    for (int i = 0; i < 4; ++i)
#pragma unroll
        for (int j = 0; j < 4; ++j) {
            int col = bn + wn * 64 + j * 16 + (lane & 15);
#pragma unroll
            for (int r = 0; r < 4; ++r) {
                int row = bm + wm * 64 + i * 16 + (lane >> 4) * 4 + r;
                float v = acc[i][j][r];
                if (MODE == 0) {
                    unsigned short h = f2bf(v);
                    unsigned short lo = f2bf(v - bf2f(h));
                    ((unsigned short*)Cout0)[(size_t)row * ldc + col] = h;
                    ((unsigned short*)Cout1)[(size_t)row * ldc + col] = lo;
                } else {
                    v += Dvec[col] * X[(size_t)row * ldc + col];
                    ((float*)Cout0)[(size_t)row * ldc + col] = v;
                }
            }
        }
}

// ---------------------------------------------------------------------------
// Scan phase A (f64 accum): per-chunk fold. bx read from bf16 hi/lo arrays.
// ---------------------------------------------------------------------------
__global__ __launch_bounds__(512) void scanA_kernel(
    const unsigned short* __restrict__ Shi, const unsigned short* __restrict__ Slo,
    const float* __restrict__ mask, const double* __restrict__ lbar,
    double* __restrict__ cA, double* __restrict__ cS, float* __restrict__ cC) {
    int p = threadIdx.x;
    int blk = blockIdx.x;
    double lbr = lbar[2 * p], lbi = lbar[2 * p + 1];
    double Ar = 1., Ai = 0., Sr = 0., Si = 0.;
    float C = 0.f;
    const ushort2* H2 = (const ushort2*)Shi;
    const ushort2* L2 = (const ushort2*)Slo;
    int t0 = blk * CS;
    for (int t = t0; t < t0 + CS; ++t) {
        float m = mask[t];
        ushort2 h2 = H2[(size_t)t * P_DIM + p];
        ushort2 l2 = L2[(size_t)t * P_DIM + p];
        double bxr = (double)(bf2f(h2.x) + bf2f(l2.x));
        double bxi = (double)(bf2f(h2.y) + bf2f(l2.y));
        if (m != 0.f) {
            Ar = lbr; Ai = lbi; Sr = bxr; Si = bxi; C = 1.f;
        } else {
            double nAr = lbr * Ar - lbi * Ai;
            Ai = lbr * Ai + lbi * Ar; Ar = nAr;
            double nSr = lbr * Sr - lbi * Si + bxr;
            Si = lbr * Si + lbi * Sr + bxi; Sr = nSr;
        }
    }
    cA[(size_t)blk * 1024 + 2 * p] = Ar;
    cA[(size_t)blk * 1024 + 2 * p + 1] = Ai;
    cS[(size_t)blk * 1024 + 2 * p] = Sr;
    cS[(size_t)blk * 1024 + 2 * p + 1] = Si;
    cC[(size_t)blk * P_DIM + p] = C;
}

// ---------------------------------------------------------------------------
// Scan phase B (f64, parallel): one block per p, Kogge-Stone over chunks.
// ---------------------------------------------------------------------------
__global__ __launch_bounds__(256) void scanB_kernel(
    const double* __restrict__ cA, const double* __restrict__ cS,
    const float* __restrict__ cC, const float* __restrict__ carry,
    double* __restrict__ prefix) {
    int p = blockIdx.x;      // 0..511
    int i = threadIdx.x;     // chunk 0..255
    __shared__ double sAr[NB], sAi[NB], sSr[NB], sSi[NB];
    __shared__ float sC[NB];

    double Ar = cA[(size_t)i * 1024 + 2 * p];
    double Ai = cA[(size_t)i * 1024 + 2 * p + 1];
    double Sr = cS[(size_t)i * 1024 + 2 * p];
    double Si = cS[(size_t)i * 1024 + 2 * p + 1];
    float  C  = cC[(size_t)i * P_DIM + p];
    sAr[i] = Ar; sAi[i] = Ai; sSr[i] = Sr; sSi[i] = Si; sC[i] = C;
    __syncthreads();

    for (int step = 1; step < NB; step <<= 1) {
        double pAr = 0, pAi = 0, pSr = 0, pSi = 0; float pC = 0;
        if (i >= step) {
            pAr = sAr[i - step]; pAi = sAi[i - step];
            pSr = sSr[i - step]; pSi = sSi[i - step]; pC = sC[i - step];
        }
        __syncthreads();
        if (i >= step && C == 0.f) {
            double nAr = Ar * pAr - Ai * pAi;
            double nAi = Ar * pAi + Ai * pAr;
            double nSr = Ar * pSr - Ai * pSi + Sr;
            double nSi = Ar * pSi + Ai * pSr + Si;
            Ar = nAr; Ai = nAi; Sr = nSr; Si = nSi; C = pC;
        }
        sAr[i] = Ar; sAi[i] = Ai; sSr[i] = Sr; sSi[i] = Si; sC[i] = C;
        __syncthreads();
    }

    double c0r = (double)carry[2 * p], c0i = (double)carry[2 * p + 1];
    double pr, pi_;
    if (i == 0) {
        pr = c0r; pi_ = c0i;
    } else {
        double Lr = sAr[i - 1], Li = sAi[i - 1];
        double Tr = sSr[i - 1], Ti = sSi[i - 1];
        float  LC = sC[i - 1];
        if (LC != 0.f) { pr = Tr; pi_ = Ti; }
        else {
            pr  = Lr * c0r - Li * c0i + Tr;
            pi_ = Lr * c0i + Li * c0r + Ti;
        }
    }
    prefix[(size_t)i * 1024 + 2 * p]     = pr;
    prefix[(size_t)i * 1024 + 2 * p + 1] = pi_;
}

// ---------------------------------------------------------------------------
// Scan phase C (f64): re-scan each chunk; write states as bf16 hi/lo
// (in place over bx). Last chunk writes final carry to d_out.
// ---------------------------------------------------------------------------
__global__ __launch_bounds__(512) void scanC_kernel(
    unsigned short* __restrict__ Shi, unsigned short* __restrict__ Slo,
    const float* __restrict__ mask, const double* __restrict__ lbar,
    const double* __restrict__ prefix,
    float* __restrict__ carry_out, int carry_elems) {
    int p = threadIdx.x;
    int blk = blockIdx.x;
    double lbr = lbar[2 * p], lbi = lbar[2 * p + 1];
    double sr = prefix[(size_t)blk * 1024 + 2 * p];
    double si = prefix[(size_t)blk * 1024 + 2 * p + 1];
    ushort2* H2 = (ushort2*)Shi;
    ushort2* L2 = (ushort2*)Slo;
    int t0 = blk * CS;
    for (int t = t0; t < t0 + CS; ++t) {
        float m = mask[t];
        ushort2 h2 = H2[(size_t)t * P_DIM + p];
        ushort2 l2 = L2[(size_t)t * P_DIM + p];
        double bxr = (double)(bf2f(h2.x) + bf2f(l2.x));
        double bxi = (double)(bf2f(h2.y) + bf2f(l2.y));
        if (m != 0.f) {
            sr = bxr; si = bxi;
        } else {
            double nr = lbr * sr - lbi * si + bxr;
            si = lbr * si + lbi * sr + bxi;
            sr = nr;
        }
        float sf = (float)sr, sif = (float)si;
        ushort2 ho, lo;
        ho.x = f2bf(sf);  lo.x = f2bf(sf - bf2f(ho.x));
        ho.y = f2bf(sif); lo.y = f2bf(sif - bf2f(ho.y));
        H2[(size_t)t * P_DIM + p] = ho;
        L2[(size_t)t * P_DIM + p] = lo;
    }
    if (blk == NB - 1) {
        if (carry_elems >= 1024) {
            carry_out[2 * p] = (float)sr;
            carry_out[2 * p + 1] = (float)si;
        } else {
            carry_out[p] = (float)sr;   // real part only
        }
    }
}

// ---------------------------------------------------------------------------
extern "C" void kernel_launch(void* const* d_in, const int* in_sizes, int n_in,
                              void* d_out, int out_size, void* d_ws, size_t ws_size,
                              hipStream_t stream) {
    const float* x           = (const float*)d_in[0];  // T*H
    const float* mask        = (const float*)d_in[1];  // T
    const float* carry       = (const float*)d_in[2];  // 1*P*2
    const float* lambda_real = (const float*)d_in[3];  // P
    const float* lambda_imag = (const float*)d_in[4];  // P
    const float* b           = (const float*)d_in[5];  // P*H*2
    const float* c           = (const float*)d_in[6];  // H*P*2
    const float* d           = (const float*)d_in[7];  // H
    const float* log_step    = (const float*)d_in[8];  // P*1

    float* out = (float*)d_out;
    char* ws = (char*)d_ws;

    int carry_elems = out_size - T_LEN * H_DIM;
    if (carry_elems != 512 && carry_elems != 1024) carry_elems = 1024;
    float* ys_out = out + carry_elems;

    // workspace layout: 8B-aligned first, then 4B, then 2B
    double* lbar   = (double*)ws;                        ws += 1024 * 8;
    double* coef   = (double*)ws;                        ws += 1024 * 8;
    double* cA     = (double*)ws;                        ws += (size_t)NB * 1024 * 8;
    double* cSb    = (double*)ws;                        ws += (size_t)NB * 1024 * 8;
    double* prefix = (double*)ws;                        ws += (size_t)NB * 1024 * 8;
    float* cC      = (float*)ws;                         ws += (size_t)NB * P_DIM * 4;
    unsigned short* xhi   = (unsigned short*)ws;         ws += (size_t)T_LEN * H_DIM * 2;
    unsigned short* xlo   = (unsigned short*)ws;         ws += (size_t)T_LEN * H_DIM * 2;
    unsigned short* Bt1hi = (unsigned short*)ws;         ws += (size_t)(2 * P_DIM) * H_DIM * 2;
    unsigned short* Bt1lo = (unsigned short*)ws;         ws += (size_t)(2 * P_DIM) * H_DIM * 2;
    unsigned short* Bt2hi = (unsigned short*)ws;         ws += (size_t)H_DIM * (2 * P_DIM) * 2;
    unsigned short* Bt2lo = (unsigned short*)ws;         ws += (size_t)H_DIM * (2 * P_DIM) * 2;
    unsigned short* Shi   = (unsigned short*)ws;         ws += (size_t)T_LEN * (2 * P_DIM) * 2;
    unsigned short* Slo   = (unsigned short*)ws;         ws += (size_t)T_LEN * (2 * P_DIM) * 2;

    // 1) precompute
    precompute_p1<<<1, 512, 0, stream>>>(lambda_real, lambda_imag, log_step,
                                         lbar, coef);
    conv_x_kernel<<<(T_LEN * H_DIM / 2) / 256, 256, 0, stream>>>(x, xhi, xlo);
    fillB_kernel<<<(P_DIM * H_DIM) / 256, 256, 0, stream>>>(b, c, coef,
                                                            Bt1hi, Bt1lo,
                                                            Bt2hi, Bt2lo);

    // 2) GEMM1 (MFMA split-bf16): S[T x 2P] = x @ bbar^T, output bf16 hi/lo
    {
        dim3 grid((2 * P_DIM) / 128, T_LEN / 128);
        gemm_mfma_split<0><<<grid, 256, 0, stream>>>(
            xhi, xlo, H_DIM, Bt1hi, Bt1lo, H_DIM,
            Shi, Slo, 2 * P_DIM, H_DIM, nullptr, nullptr);
    }

    // 3) chunked scan over T (f64 state arithmetic)
    scanA_kernel<<<NB, 512, 0, stream>>>(Shi, Slo, mask, lbar, cA, cSb, cC);
    scanB_kernel<<<P_DIM, NB, 0, stream>>>(cA, cSb, cC, carry, prefix);
    scanC_kernel<<<NB, 512, 0, stream>>>(Shi, Slo, mask, lbar, prefix, out,
                                         carry_elems);

    // 4) GEMM2 (MFMA split-bf16): ys[T x H] = S @ B2 + d*x -> f32
    {
        dim3 grid(H_DIM / 128, T_LEN / 128);
        gemm_mfma_split<1><<<grid, 256, 0, stream>>>(
            Shi, Slo, 2 * P_DIM, Bt2hi, Bt2lo, 2 * P_DIM,
            ys_out, nullptr, H_DIM, 2 * P_DIM, d, x);
    }
}

// Round 7
// 116.080 us; speedup vs baseline: 5.1852x; 1.0515x over previous
//
#include <hip/hip_runtime.h>
#include <hip/hip_bf16.h>

#define T_LEN 8192
#define H_DIM 512
#define P_DIM 512
#define CS 32
#define NB (T_LEN / CS)   // 256 chunks

typedef __attribute__((ext_vector_type(8))) __bf16 bf16x8;
typedef __attribute__((ext_vector_type(4))) float f32x4;

__device__ __forceinline__ unsigned short f2bf(float f) {
    __bf16 h = (__bf16)f;
    return __builtin_bit_cast(unsigned short, h);
}
__device__ __forceinline__ float bf2f(unsigned short u) {
    unsigned v = ((unsigned)u) << 16;
    return __builtin_bit_cast(float, v);
}

__device__ __forceinline__ void gload_lds16(void* g, void* l) {
    __builtin_amdgcn_global_load_lds(
        (__attribute__((address_space(1))) unsigned*)g,
        (__attribute__((address_space(3))) unsigned*)l, 16, 0, 0);
}

// ---------------------------------------------------------------------------
// P1: per-p lambda_bar (f64) and coef = (lbar-1)/lam (f64). One block.
// ---------------------------------------------------------------------------
__global__ __launch_bounds__(512) void precompute_p1(
    const float* __restrict__ lambda_real,
    const float* __restrict__ lambda_imag,
    const float* __restrict__ log_step,
    double* __restrict__ lbar,
    double* __restrict__ coef) {
    int p = threadIdx.x;
    double lr = fmin((double)lambda_real[p], -1e-4);
    double li = (double)lambda_imag[p];
    double step = exp((double)log_step[p]);          // STEP_RESCALE = 1
    double er = exp(lr * step);
    double ang = li * step;
    double lbr = er * cos(ang);
    double lbi = er * sin(ang);
    lbar[2 * p] = lbr;
    lbar[2 * p + 1] = lbi;
    double nr = lbr - 1.0, ni = lbi;
    double den = lr * lr + li * li;
    coef[2 * p]     = (nr * lr + ni * li) / den;
    coef[2 * p + 1] = (ni * lr - nr * li) / den;
}

// ---------------------------------------------------------------------------
// prep: ALL 8192 blocks: x (f32) -> xhi/xlo bf16 split (2 floats/thread).
//       blocks < 1024 additionally fill Bt1 (coef*b~, transposed) and
//       Bt2 (from c, layout-native) as bf16 hi/lo.
// ---------------------------------------------------------------------------
__global__ __launch_bounds__(256) void prep_kernel(
    const float* __restrict__ x,
    const float* __restrict__ b, const float* __restrict__ c,
    const double* __restrict__ coef,
    unsigned short* __restrict__ xhi, unsigned short* __restrict__ xlo,
    unsigned short* __restrict__ Bt1hi, unsigned short* __restrict__ Bt1lo,
    unsigned short* __restrict__ Bt2hi, unsigned short* __restrict__ Bt2lo) {
    int idx = blockIdx.x * 256 + threadIdx.x;        // 0 .. T*H/2-1
    {
        float2 v = ((const float2*)x)[idx];
        ushort2 h, l;
        h.x = f2bf(v.x); l.x = f2bf(v.x - bf2f(h.x));
        h.y = f2bf(v.y); l.y = f2bf(v.y - bf2f(h.y));
        ((ushort2*)xhi)[idx] = h;
        ((ushort2*)xlo)[idx] = l;
    }
    if (blockIdx.x < (P_DIM * H_DIM) / 256) {
        {   // Bt1: rows 2p,2p+1 (stride H_DIM), coalesced in h
            int p = idx >> 9, h = idx & 511;
            double cr = coef[2 * p], ci = coef[2 * p + 1];
            float2 bv = ((const float2*)b)[(size_t)p * H_DIM + h];
            float re = (float)(cr * (double)bv.x - ci * (double)bv.y);
            float im = (float)(cr * (double)bv.y + ci * (double)bv.x);
            unsigned short rh = f2bf(re), ih = f2bf(im);
            Bt1hi[(size_t)(2 * p) * H_DIM + h]     = rh;
            Bt1lo[(size_t)(2 * p) * H_DIM + h]     = f2bf(re - bf2f(rh));
            Bt1hi[(size_t)(2 * p + 1) * H_DIM + h] = ih;
            Bt1lo[(size_t)(2 * p + 1) * H_DIM + h] = f2bf(im - bf2f(ih));
        }
        {   // Bt2: row h (stride 2P), cols 2p,2p+1 -> ushort2, coalesced in p
            int h = idx >> 9, p = idx & 511;
            float2 cv = ((const float2*)c)[(size_t)h * P_DIM + p];
            float re = cv.x, im = -cv.y;
            ushort2 hi, lo;
            hi.x = f2bf(re); lo.x = f2bf(re - bf2f(hi.x));
            hi.y = f2bf(im); lo.y = f2bf(im - bf2f(hi.y));
            ((ushort2*)Bt2hi)[(size_t)h * P_DIM + p] = hi;
            ((ushort2*)Bt2lo)[(size_t)h * P_DIM + p] = lo;
        }
    }
}

// ---------------------------------------------------------------------------
// Split-bf16 MFMA GEMM: C[M x N] = (Ahi+Alo)[M x K] * (Bhi+Blo)^T-staged
// B given TRANSPOSED: Bt[n][k]. 128x128 tile, BK=32, 256 thr = 4 waves (2x2).
// 3 MFMA passes (hh, hl, lh), fp32 accumulate.
// MODE 0: write C as bf16 hi/lo split (Cout0/Cout1).
// MODE 1: write f32 C + D[col]*X[row][col] into Cout0.
// LDS tiles [128 rows][32 shorts=64B], chunk-swizzled: pos = c ^ ((row>>1)&3).
// XCD-aware block swizzle: XCD k owns a compact (gy/8)-row x all-col region
// so A-panels are fetched to one XCD L2 only. Requires gridDim.y % 8 == 0.
// ---------------------------------------------------------------------------
template <int MODE>
__global__ __launch_bounds__(256) void gemm_mfma_split(
    const unsigned short* __restrict__ Ahi, const unsigned short* __restrict__ Alo,
    int lda,
    const unsigned short* __restrict__ Bthi, const unsigned short* __restrict__ Btlo,
    int ldb,
    void* __restrict__ Cout0, void* __restrict__ Cout1, int ldc, int K,
    const float* __restrict__ Dvec, const float* __restrict__ X) {
    __shared__ __align__(16) unsigned short lds[2][4][128 * 32];
    const int tid = threadIdx.x;
    const int lane = tid & 63, wid = tid >> 6;
    const int wm = wid >> 1, wn = wid & 1;

    // XCD swizzle (bijective: gy % 8 == 0)
    const int id = blockIdx.y * gridDim.x + blockIdx.x;
    const int nx = gridDim.x, rpx = gridDim.y >> 3;
    const int xcd = id & 7, j = id >> 3;
    const int by = xcd * rpx + j / nx;
    const int bx = j % nx;
    const int bm = by * 128, bn = bx * 128;

    // staging source for this wave: tile wid of {Ahi, Alo, Bthi, Btlo}
    const unsigned short* ssrc;
    int srow0, sld;
    if (wid == 0)      { ssrc = Ahi;  srow0 = bm; sld = lda; }
    else if (wid == 1) { ssrc = Alo;  srow0 = bm; sld = lda; }
    else if (wid == 2) { ssrc = Bthi; srow0 = bn; sld = ldb; }
    else               { ssrc = Btlo; srow0 = bn; sld = ldb; }

    f32x4 acc[4][4];
#pragma unroll
    for (int i = 0; i < 4; ++i)
#pragma unroll
        for (int j2 = 0; j2 < 4; ++j2) acc[i][j2] = (f32x4)(0.0f);

    // stage one [128][32] bf16 tile (8 KB) = 8 x 1024B instructions
    auto stage = [&](int buf, int k0) {
        unsigned short* base = &lds[buf][wid][0];
#pragma unroll
        for (int s = 0; s < 8; ++s) {
            int r = s * 16 + (lane >> 2);
            int cg = (lane & 3) ^ ((r >> 1) & 3);
            void* g = (void*)((const char*)(ssrc + (size_t)(srow0 + r) * sld + k0)
                              + cg * 16);
            gload_lds16(g, (void*)((char*)base + s * 1024));
        }
    };

    stage(0, 0);
    __syncthreads();   // drains vmcnt

    const int nk = K / 32;
    for (int t = 0; t < nk; ++t) {
        int cur = t & 1;
        if (t + 1 < nk) stage(cur ^ 1, (t + 1) * 32);

        bf16x8 ah[4], al[4], bh[4], bl[4];
#pragma unroll
        for (int i = 0; i < 4; ++i) {
            int rA = wm * 64 + i * 16 + (lane & 15);
            int byA = rA * 64 + ((((lane >> 4)) ^ ((rA >> 1) & 3)) << 4);
            ah[i] = *(const bf16x8*)((const char*)&lds[cur][0][0] + byA);
            al[i] = *(const bf16x8*)((const char*)&lds[cur][1][0] + byA);
            int rB = wn * 64 + i * 16 + (lane & 15);
            int byB = rB * 64 + ((((lane >> 4)) ^ ((rB >> 1) & 3)) << 4);
            bh[i] = *(const bf16x8*)((const char*)&lds[cur][2][0] + byB);
            bl[i] = *(const bf16x8*)((const char*)&lds[cur][3][0] + byB);
        }
#pragma unroll
        for (int i = 0; i < 4; ++i)
#pragma unroll
            for (int j2 = 0; j2 < 4; ++j2) {
                acc[i][j2] = __builtin_amdgcn_mfma_f32_16x16x32_bf16(
                    ah[i], bh[j2], acc[i][j2], 0, 0, 0);
                acc[i][j2] = __builtin_amdgcn_mfma_f32_16x16x32_bf16(
                    ah[i], bl[j2], acc[i][j2], 0, 0, 0);
                acc[i][j2] = __builtin_amdgcn_mfma_f32_16x16x32_bf16(
                    al[i], bh[j2], acc[i][j2], 0, 0, 0);
            }
        __syncthreads();
    }

    // epilogue. C/D map (verified m89/m91): col = lane&15, row = 4*(lane>>4)+reg
#pragma unroll
    for (int i = 0; i < 4; ++i)
#pragma unroll
        for (int j2 = 0; j2 < 4; ++j2) {
            int col = bn + wn * 64 + j2 * 16 + (lane & 15);
#pragma unroll
            for (int r = 0; r < 4; ++r) {
                int row = bm + wm * 64 + i * 16 + (lane >> 4) * 4 + r;
                float v = acc[i][j2][r];
                if (MODE == 0) {
                    unsigned short h = f2bf(v);
                    unsigned short lo = f2bf(v - bf2f(h));
                    ((unsigned short*)Cout0)[(size_t)row * ldc + col] = h;
                    ((unsigned short*)Cout1)[(size_t)row * ldc + col] = lo;
                } else {
                    v += Dvec[col] * X[(size_t)row * ldc + col];
                    ((float*)Cout0)[(size_t)row * ldc + col] = v;
                }
            }
        }
}

// ---------------------------------------------------------------------------
// Scan phase A (f64 accum): per-chunk fold. bx read from bf16 hi/lo arrays.
// ---------------------------------------------------------------------------
__global__ __launch_bounds__(512) void scanA_kernel(
    const unsigned short* __restrict__ Shi, const unsigned short* __restrict__ Slo,
    const float* __restrict__ mask, const double* __restrict__ lbar,
    double* __restrict__ cA, double* __restrict__ cS, float* __restrict__ cC) {
    int p = threadIdx.x;
    int blk = blockIdx.x;
    double lbr = lbar[2 * p], lbi = lbar[2 * p + 1];
    double Ar = 1., Ai = 0., Sr = 0., Si = 0.;
    float C = 0.f;
    const ushort2* H2 = (const ushort2*)Shi;
    const ushort2* L2 = (const ushort2*)Slo;
    int t0 = blk * CS;
    for (int t = t0; t < t0 + CS; ++t) {
        float m = mask[t];
        ushort2 h2 = H2[(size_t)t * P_DIM + p];
        ushort2 l2 = L2[(size_t)t * P_DIM + p];
        double bxr = (double)(bf2f(h2.x) + bf2f(l2.x));
        double bxi = (double)(bf2f(h2.y) + bf2f(l2.y));
        if (m != 0.f) {
            Ar = lbr; Ai = lbi; Sr = bxr; Si = bxi; C = 1.f;
        } else {
            double nAr = lbr * Ar - lbi * Ai;
            Ai = lbr * Ai + lbi * Ar; Ar = nAr;
            double nSr = lbr * Sr - lbi * Si + bxr;
            Si = lbr * Si + lbi * Sr + bxi; Sr = nSr;
        }
    }
    cA[(size_t)blk * 1024 + 2 * p] = Ar;
    cA[(size_t)blk * 1024 + 2 * p + 1] = Ai;
    cS[(size_t)blk * 1024 + 2 * p] = Sr;
    cS[(size_t)blk * 1024 + 2 * p + 1] = Si;
    cC[(size_t)blk * P_DIM + p] = C;
}

// ---------------------------------------------------------------------------
// Scan phase B (f64, parallel): one block per p, Kogge-Stone over chunks.
// ---------------------------------------------------------------------------
__global__ __launch_bounds__(256) void scanB_kernel(
    const double* __restrict__ cA, const double* __restrict__ cS,
    const float* __restrict__ cC, const float* __restrict__ carry,
    double* __restrict__ prefix) {
    int p = blockIdx.x;      // 0..511
    int i = threadIdx.x;     // chunk 0..255
    __shared__ double sAr[NB], sAi[NB], sSr[NB], sSi[NB];
    __shared__ float sC[NB];

    double Ar = cA[(size_t)i * 1024 + 2 * p];
    double Ai = cA[(size_t)i * 1024 + 2 * p + 1];
    double Sr = cS[(size_t)i * 1024 + 2 * p];
    double Si = cS[(size_t)i * 1024 + 2 * p + 1];
    float  C  = cC[(size_t)i * P_DIM + p];
    sAr[i] = Ar; sAi[i] = Ai; sSr[i] = Sr; sSi[i] = Si; sC[i] = C;
    __syncthreads();

    for (int step = 1; step < NB; step <<= 1) {
        double pAr = 0, pAi = 0, pSr = 0, pSi = 0; float pC = 0;
        if (i >= step) {
            pAr = sAr[i - step]; pAi = sAi[i - step];
            pSr = sSr[i - step]; pSi = sSi[i - step]; pC = sC[i - step];
        }
        __syncthreads();
        if (i >= step && C == 0.f) {
            double nAr = Ar * pAr - Ai * pAi;
            double nAi = Ar * pAi + Ai * pAr;
            double nSr = Ar * pSr - Ai * pSi + Sr;
            double nSi = Ar * pSi + Ai * pSr + Si;
            Ar = nAr; Ai = nAi; Sr = nSr; Si = nSi; C = pC;
        }
        sAr[i] = Ar; sAi[i] = Ai; sSr[i] = Sr; sSi[i] = Si; sC[i] = C;
        __syncthreads();
    }

    double c0r = (double)carry[2 * p], c0i = (double)carry[2 * p + 1];
    double pr, pi_;
    if (i == 0) {
        pr = c0r; pi_ = c0i;
    } else {
        double Lr = sAr[i - 1], Li = sAi[i - 1];
        double Tr = sSr[i - 1], Ti = sSi[i - 1];
        float  LC = sC[i - 1];
        if (LC != 0.f) { pr = Tr; pi_ = Ti; }
        else {
            pr  = Lr * c0r - Li * c0i + Tr;
            pi_ = Lr * c0i + Li * c0r + Ti;
        }
    }
    prefix[(size_t)i * 1024 + 2 * p]     = pr;
    prefix[(size_t)i * 1024 + 2 * p + 1] = pi_;
}

// ---------------------------------------------------------------------------
// Scan phase C (f64): re-scan each chunk; write states as bf16 hi/lo
// (in place over bx). Last chunk writes final carry to d_out.
// ---------------------------------------------------------------------------
__global__ __launch_bounds__(512) void scanC_kernel(
    unsigned short* __restrict__ Shi, unsigned short* __restrict__ Slo,
    const float* __restrict__ mask, const double* __restrict__ lbar,
    const double* __restrict__ prefix,
    float* __restrict__ carry_out, int carry_elems) {
    int p = threadIdx.x;
    int blk = blockIdx.x;
    double lbr = lbar[2 * p], lbi = lbar[2 * p + 1];
    double sr = prefix[(size_t)blk * 1024 + 2 * p];
    double si = prefix[(size_t)blk * 1024 + 2 * p + 1];
    ushort2* H2 = (ushort2*)Shi;
    ushort2* L2 = (ushort2*)Slo;
    int t0 = blk * CS;
    for (int t = t0; t < t0 + CS; ++t) {
        float m = mask[t];
        ushort2 h2 = H2[(size_t)t * P_DIM + p];
        ushort2 l2 = L2[(size_t)t * P_DIM + p];
        double bxr = (double)(bf2f(h2.x) + bf2f(l2.x));
        double bxi = (double)(bf2f(h2.y) + bf2f(l2.y));
        if (m != 0.f) {
            sr = bxr; si = bxi;
        } else {
            double nr = lbr * sr - lbi * si + bxr;
            si = lbr * si + lbi * sr + bxi;
            sr = nr;
        }
        float sf = (float)sr, sif = (float)si;
        ushort2 ho, lo;
        ho.x = f2bf(sf);  lo.x = f2bf(sf - bf2f(ho.x));
        ho.y = f2bf(sif); lo.y = f2bf(sif - bf2f(ho.y));
        H2[(size_t)t * P_DIM + p] = ho;
        L2[(size_t)t * P_DIM + p] = lo;
    }
    if (blk == NB - 1) {
        if (carry_elems >= 1024) {
            carry_out[2 * p] = (float)sr;
            carry_out[2 * p + 1] = (float)si;
        } else {
            carry_out[p] = (float)sr;   // real part only
        }
    }
}

// ---------------------------------------------------------------------------
extern "C" void kernel_launch(void* const* d_in, const int* in_sizes, int n_in,
                              void* d_out, int out_size, void* d_ws, size_t ws_size,
                              hipStream_t stream) {
    const float* x           = (const float*)d_in[0];  // T*H
    const float* mask        = (const float*)d_in[1];  // T
    const float* carry       = (const float*)d_in[2];  // 1*P*2
    const float* lambda_real = (const float*)d_in[3];  // P
    const float* lambda_imag = (const float*)d_in[4];  // P
    const float* b           = (const float*)d_in[5];  // P*H*2
    const float* c           = (const float*)d_in[6];  // H*P*2
    const float* d           = (const float*)d_in[7];  // H
    const float* log_step    = (const float*)d_in[8];  // P*1

    float* out = (float*)d_out;
    char* ws = (char*)d_ws;

    int carry_elems = out_size - T_LEN * H_DIM;
    if (carry_elems != 512 && carry_elems != 1024) carry_elems = 1024;
    float* ys_out = out + carry_elems;

    // workspace layout: 8B-aligned first, then 4B, then 2B
    double* lbar   = (double*)ws;                        ws += 1024 * 8;
    double* coef   = (double*)ws;                        ws += 1024 * 8;
    double* cA     = (double*)ws;                        ws += (size_t)NB * 1024 * 8;
    double* cSb    = (double*)ws;                        ws += (size_t)NB * 1024 * 8;
    double* prefix = (double*)ws;                        ws += (size_t)NB * 1024 * 8;
    float* cC      = (float*)ws;                         ws += (size_t)NB * P_DIM * 4;
    unsigned short* xhi   = (unsigned short*)ws;         ws += (size_t)T_LEN * H_DIM * 2;
    unsigned short* xlo   = (unsigned short*)ws;         ws += (size_t)T_LEN * H_DIM * 2;
    unsigned short* Bt1hi = (unsigned short*)ws;         ws += (size_t)(2 * P_DIM) * H_DIM * 2;
    unsigned short* Bt1lo = (unsigned short*)ws;         ws += (size_t)(2 * P_DIM) * H_DIM * 2;
    unsigned short* Bt2hi = (unsigned short*)ws;         ws += (size_t)H_DIM * (2 * P_DIM) * 2;
    unsigned short* Bt2lo = (unsigned short*)ws;         ws += (size_t)H_DIM * (2 * P_DIM) * 2;
    unsigned short* Shi   = (unsigned short*)ws;         ws += (size_t)T_LEN * (2 * P_DIM) * 2;
    unsigned short* Slo   = (unsigned short*)ws;         ws += (size_t)T_LEN * (2 * P_DIM) * 2;

    // 1) precompute (p1: lbar/coef f64), then prep (x split + B fills)
    precompute_p1<<<1, 512, 0, stream>>>(lambda_real, lambda_imag, log_step,
                                         lbar, coef);
    prep_kernel<<<(T_LEN * H_DIM / 2) / 256, 256, 0, stream>>>(
        x, b, c, coef, xhi, xlo, Bt1hi, Bt1lo, Bt2hi, Bt2lo);

    // 2) GEMM1 (MFMA split-bf16): S[T x 2P] = x @ bbar^T, output bf16 hi/lo
    {
        dim3 grid((2 * P_DIM) / 128, T_LEN / 128);   // (8, 64)
        gemm_mfma_split<0><<<grid, 256, 0, stream>>>(
            xhi, xlo, H_DIM, Bt1hi, Bt1lo, H_DIM,
            Shi, Slo, 2 * P_DIM, H_DIM, nullptr, nullptr);
    }

    // 3) chunked scan over T (f64 state arithmetic)
    scanA_kernel<<<NB, 512, 0, stream>>>(Shi, Slo, mask, lbar, cA, cSb, cC);
    scanB_kernel<<<P_DIM, NB, 0, stream>>>(cA, cSb, cC, carry, prefix);
    scanC_kernel<<<NB, 512, 0, stream>>>(Shi, Slo, mask, lbar, prefix, out,
                                         carry_elems);

    // 4) GEMM2 (MFMA split-bf16): ys[T x H] = S @ B2 + d*x -> f32
    {
        dim3 grid(H_DIM / 128, T_LEN / 128);         // (4, 64)
        gemm_mfma_split<1><<<grid, 256, 0, stream>>>(
            Shi, Slo, 2 * P_DIM, Bt2hi, Bt2lo, 2 * P_DIM,
            ys_out, nullptr, H_DIM, 2 * P_DIM, d, x);
    }
}